// Round 3
// baseline (670.813 us; speedup 1.0000x reference)
//
#include <hip/hip_runtime.h>

#define N_NODES 100000
#define N_EDGES 3200000
#define N_FEAT 512
#define HIDDEN 16
#define N_CLASSES 40

#define SCAN_BLOCKS 98   // ceil(100000/1024)

// ---- chunked counting-sort CSR build ----
// 8 chunks (one per XCD) x 32 slices. CH nodes per chunk (51 KB LDS),
// chunk = wgid & 7 -> all WGs writing one chunk's edge range land on ONE
// XCD (dispatch round-robins blockIdx across XCDs), so scattered 8B
// edge_data stores accumulate in that XCD's L2 (chunk range ~3.3 MB < 4 MB)
// instead of write-through at 32B/edge (was 102 MB WRITE_SIZE, 4x).
#define CH    12800
#define NCH   8
#define NS    32
#define SLICE (N_EDGES / NS)       // 100000 edges per slice (exact)
#define SL4   (SLICE / 4)          // int4 loads per slice (exact)

typedef int v4i __attribute__((ext_vector_type(4)));

// Pass 1: per-(chunk, slice) partial histogram via LDS atomics.
// partS[s][n] (slice-major) -> all global writes coalesced. No global atomics.
__global__ __launch_bounds__(512) void k_p1(const int* __restrict__ dst,
                                            int* __restrict__ partS) {
    __shared__ int hist[CH];
    int tid = threadIdx.x;
    int s = blockIdx.x >> 3, j = blockIdx.x & 7;
    int base = j * CH;
    int lim = N_NODES - base; if (lim > CH) lim = CH;
    for (int i = tid; i < CH; i += 512) hist[i] = 0;
    __syncthreads();
    const v4i* dp = reinterpret_cast<const v4i*>(dst + s * SLICE);
    for (int i = tid; i < SL4; i += 512) {
        v4i d4 = __builtin_nontemporal_load(dp + i);  // keep L2 clean
        unsigned a = (unsigned)(d4.x - base); if (a < (unsigned)lim) atomicAdd(&hist[a], 1);
        unsigned b = (unsigned)(d4.y - base); if (b < (unsigned)lim) atomicAdd(&hist[b], 1);
        unsigned c = (unsigned)(d4.z - base); if (c < (unsigned)lim) atomicAdd(&hist[c], 1);
        unsigned d = (unsigned)(d4.w - base); if (d < (unsigned)lim) atomicAdd(&hist[d], 1);
    }
    __syncthreads();
    for (int i = tid; i < lim; i += 512)
        partS[s * N_NODES + base + i] = hist[i];
}

// Per-node exclusive scan across the 32 slices (in place, coalesced per slice
// step), total degree -> deg, dinv fused.
__global__ __launch_bounds__(256) void k_colscan(int* __restrict__ partS,
                                                 int* __restrict__ deg,
                                                 float* __restrict__ dinv) {
    int n = blockIdx.x * 256 + threadIdx.x;
    if (n >= N_NODES) return;
    int run = 0;
    #pragma unroll
    for (int s = 0; s < NS; s++) {
        int idx = s * N_NODES + n;
        int v = partS[idx];
        partS[idx] = run;       // exclusive-over-slices within node n
        run += v;
    }
    deg[n] = run;
    dinv[n] = rsqrtf((float)(run + 1));  // +1 self-loop
}

// ---------------- 3-phase exclusive scan of deg -> row_start ----------------

__global__ __launch_bounds__(1024) void k_scan_a(const int* __restrict__ cnt,
                                                 int* __restrict__ bsum) {
    int tid = threadIdx.x;
    int i = blockIdx.x * 1024 + tid;
    int v = (i < N_NODES) ? cnt[i] : 0;
    #pragma unroll
    for (int off = 32; off >= 1; off >>= 1) v += __shfl_xor(v, off, 64);
    __shared__ int ws[16];
    if ((tid & 63) == 0) ws[tid >> 6] = v;
    __syncthreads();
    if (tid == 0) {
        int s = 0;
        #pragma unroll
        for (int w = 0; w < 16; w++) s += ws[w];
        bsum[blockIdx.x] = s;
    }
}

__global__ __launch_bounds__(128) void k_scan_b(const int* __restrict__ bsum,
                                                int* __restrict__ boff) {
    int tid = threadIdx.x;
    int lane = tid & 63, wv = tid >> 6;
    int v = (tid < SCAN_BLOCKS) ? bsum[tid] : 0;
    int sc = v;
    #pragma unroll
    for (int off = 1; off < 64; off <<= 1) {
        int t = __shfl_up(sc, off, 64);
        if (lane >= off) sc += t;
    }
    __shared__ int wsum[2];
    if (lane == 63) wsum[wv] = sc;
    __syncthreads();
    int pre = (wv == 1) ? wsum[0] : 0;
    if (tid < SCAN_BLOCKS) boff[tid] = pre + sc - v;  // exclusive
}

__global__ __launch_bounds__(1024) void k_scan_c(const int* __restrict__ cnt,
                                                 const int* __restrict__ boff,
                                                 int* __restrict__ row_start) {
    int tid = threadIdx.x;
    int i = blockIdx.x * 1024 + tid;
    int lane = tid & 63, wv = tid >> 6;
    int v = (i < N_NODES) ? cnt[i] : 0;
    int sc = v;
    #pragma unroll
    for (int off = 1; off < 64; off <<= 1) {
        int t = __shfl_up(sc, off, 64);
        if (lane >= off) sc += t;
    }
    __shared__ int wsum[16];
    if (lane == 63) wsum[wv] = sc;
    __syncthreads();
    int pre = 0;
    #pragma unroll
    for (int w = 0; w < 16; w++) pre += (w < wv) ? wsum[w] : 0;
    int excl = boff[blockIdx.x] + pre + sc - v;
    if (i < N_NODES) row_start[i] = excl;
    if (i == N_NODES) row_start[N_NODES] = N_EDGES;
}

// Pass 2: re-stream slice (nt loads), LDS cursor = row_start + partS;
// returning LDS atomic gives each edge a unique slot. Scattered edge_data
// stores stay cached: this chunk's whole slot range lives in this XCD's L2.
__global__ __launch_bounds__(512) void k_p2(const int* __restrict__ src,
                                            const int* __restrict__ dst,
                                            const int* __restrict__ partS,
                                            const int* __restrict__ row_start,
                                            const float* __restrict__ dinv,
                                            int2* __restrict__ edge_data) {
    __shared__ int cur[CH];
    int tid = threadIdx.x;
    int s = blockIdx.x >> 3, j = blockIdx.x & 7;
    int base = j * CH;
    int lim = N_NODES - base; if (lim > CH) lim = CH;
    for (int i = tid; i < lim; i += 512)
        cur[i] = row_start[base + i] + partS[s * N_NODES + base + i];
    __syncthreads();
    const v4i* dp = reinterpret_cast<const v4i*>(dst + s * SLICE);
    const v4i* sp = reinterpret_cast<const v4i*>(src + s * SLICE);
    for (int i = tid; i < SL4; i += 512) {
        v4i d4 = __builtin_nontemporal_load(dp + i);
        v4i s4 = __builtin_nontemporal_load(sp + i);
        {
            unsigned nl = (unsigned)(d4.x - base);
            if (nl < (unsigned)lim) {
                int slot = atomicAdd(&cur[nl], 1);
                edge_data[slot] = make_int2(s4.x, __float_as_int(dinv[s4.x] * dinv[d4.x]));
            }
        }
        {
            unsigned nl = (unsigned)(d4.y - base);
            if (nl < (unsigned)lim) {
                int slot = atomicAdd(&cur[nl], 1);
                edge_data[slot] = make_int2(s4.y, __float_as_int(dinv[s4.y] * dinv[d4.y]));
            }
        }
        {
            unsigned nl = (unsigned)(d4.z - base);
            if (nl < (unsigned)lim) {
                int slot = atomicAdd(&cur[nl], 1);
                edge_data[slot] = make_int2(s4.z, __float_as_int(dinv[s4.z] * dinv[d4.z]));
            }
        }
        {
            unsigned nl = (unsigned)(d4.w - base);
            if (nl < (unsigned)lim) {
                int slot = atomicAdd(&cur[nl], 1);
                edge_data[slot] = make_int2(s4.w, __float_as_int(dinv[s4.w] * dinv[d4.w]));
            }
        }
    }
}

// ---------------- GEMM1: h1[N,16] = x[N,512] @ W1[512,16] ----------------
// 256 rows/block, thread owns one row. K chunked by 32, staged dense in LDS
// ([256][36] pad -> bank-balanced b128 reads/writes). W1 read at wave-uniform
// indices -> scalar-cache s_load, off the VMEM pipe.

#define KC 32
#define LDSW 36

__global__ __launch_bounds__(256) void k_gemm1(const float* __restrict__ x,
                                               const float* __restrict__ W1,
                                               float* __restrict__ h1) {
    __shared__ float xs[256 * LDSW];
    int tid = threadIdx.x;
    int row = blockIdx.x * 256 + tid;

    float acc[HIDDEN];
    #pragma unroll
    for (int j = 0; j < HIDDEN; j++) acc[j] = 0.f;

    int s_sub = tid >> 3;  // 0..31 staging row-sub
    int s_k4  = tid & 7;   // 0..7  staging k4

    for (int kc = 0; kc < N_FEAT; kc += KC) {
        __syncthreads();  // previous chunk's reads done before overwrite
        #pragma unroll
        for (int l = 0; l < 8; l++) {
            int srow = s_sub + l * 32;
            int grow = blockIdx.x * 256 + srow;
            int gr = grow < N_NODES ? grow : N_NODES - 1;  // clamp
            float4 v = *reinterpret_cast<const float4*>(
                x + (size_t)gr * N_FEAT + kc + s_k4 * 4);
            *reinterpret_cast<float4*>(&xs[srow * LDSW + s_k4 * 4]) = v;
        }
        __syncthreads();

        const float* Wc = W1 + kc * HIDDEN;  // wave-uniform
        #pragma unroll
        for (int k4 = 0; k4 < 8; k4++) {
            float4 xv = *reinterpret_cast<const float4*>(&xs[tid * LDSW + k4 * 4]);
            const float* w0 = Wc + (k4 * 4 + 0) * HIDDEN;
            const float* w1 = Wc + (k4 * 4 + 1) * HIDDEN;
            const float* w2 = Wc + (k4 * 4 + 2) * HIDDEN;
            const float* w3 = Wc + (k4 * 4 + 3) * HIDDEN;
            #pragma unroll
            for (int j = 0; j < HIDDEN; j++) {
                acc[j] += xv.x * w0[j];
                acc[j] += xv.y * w1[j];
                acc[j] += xv.z * w2[j];
                acc[j] += xv.w * w3[j];
            }
        }
    }

    if (row < N_NODES) {
        float4* op = reinterpret_cast<float4*>(h1 + (size_t)row * HIDDEN);
        #pragma unroll
        for (int q = 0; q < 4; q++)
            op[q] = make_float4(acc[q*4+0], acc[q*4+1], acc[q*4+2], acc[q*4+3]);
    }
}

// ---------------- CSR aggregation over 16 features ----------------
// 16 threads per node, 16 nodes/block. 4-wide edge unroll for MLP.

template <bool RELU>
__global__ __launch_bounds__(256) void k_agg16(const int2* __restrict__ edge_data,
                                               const int* __restrict__ row_start,
                                               const float* __restrict__ dinv,
                                               const float* __restrict__ h,
                                               const float* __restrict__ bias,
                                               float* __restrict__ out) {
    int g = threadIdx.x >> 4, j = threadIdx.x & 15;
    int node = blockIdx.x * 16 + g;
    if (node >= N_NODES) return;
    int beg = row_start[node], end = row_start[node + 1];
    float ds = dinv[node];
    float acc = h[(size_t)node * HIDDEN + j] * (ds * ds);  // self loop
    int i = beg;
    for (; i + 3 < end; i += 4) {
        int2 e0 = edge_data[i + 0];
        int2 e1 = edge_data[i + 1];
        int2 e2 = edge_data[i + 2];
        int2 e3 = edge_data[i + 3];
        float v0 = h[(size_t)e0.x * HIDDEN + j];
        float v1 = h[(size_t)e1.x * HIDDEN + j];
        float v2 = h[(size_t)e2.x * HIDDEN + j];
        float v3 = h[(size_t)e3.x * HIDDEN + j];
        acc += v0 * __int_as_float(e0.y);
        acc += v1 * __int_as_float(e1.y);
        acc += v2 * __int_as_float(e2.y);
        acc += v3 * __int_as_float(e3.y);
    }
    for (; i < end; ++i) {
        int2 ed = edge_data[i];
        acc += h[(size_t)ed.x * HIDDEN + j] * __int_as_float(ed.y);
    }
    if (RELU) acc = fmaxf(acc + bias[j], 0.f);
    out[(size_t)node * HIDDEN + j] = acc;
}

// ---------------- final: out = agg2 @ W2 + b2, log_softmax ----------------

__global__ __launch_bounds__(256) void k_out(const float* __restrict__ agg2,
                                             const float* __restrict__ W2,
                                             const float* __restrict__ b2,
                                             float* __restrict__ out) {
    int r = blockIdx.x * 256 + threadIdx.x;
    if (r >= N_NODES) return;
    float a[HIDDEN];
    const float4* ap = reinterpret_cast<const float4*>(agg2 + (size_t)r * HIDDEN);
    #pragma unroll
    for (int q = 0; q < 4; q++) {
        float4 v = ap[q];
        a[q * 4 + 0] = v.x; a[q * 4 + 1] = v.y;
        a[q * 4 + 2] = v.z; a[q * 4 + 3] = v.w;
    }
    float acc[N_CLASSES];
    #pragma unroll
    for (int jj = 0; jj < N_CLASSES; jj++) acc[jj] = b2[jj];
    #pragma unroll
    for (int kk = 0; kk < HIDDEN; kk++) {
        float av = a[kk];
        #pragma unroll
        for (int jj = 0; jj < N_CLASSES; jj++)
            acc[jj] += av * W2[kk * N_CLASSES + jj];  // uniform -> scalar loads
    }
    float m = -1e30f;
    #pragma unroll
    for (int jj = 0; jj < N_CLASSES; jj++) m = fmaxf(m, acc[jj]);
    float sum = 0.f;
    #pragma unroll
    for (int jj = 0; jj < N_CLASSES; jj++) sum += __expf(acc[jj] - m);
    float l = m + __logf(sum);
    float4* op = reinterpret_cast<float4*>(out + (size_t)r * N_CLASSES);
    #pragma unroll
    for (int q = 0; q < N_CLASSES / 4; q++) {
        op[q] = make_float4(acc[q*4+0] - l, acc[q*4+1] - l,
                            acc[q*4+2] - l, acc[q*4+3] - l);
    }
}

// ---------------- launch ----------------

extern "C" void kernel_launch(void* const* d_in, const int* in_sizes, int n_in,
                              void* d_out, int out_size, void* d_ws, size_t ws_size,
                              hipStream_t stream) {
    const float* x  = (const float*)d_in[0];
    const int*   ei = (const int*)d_in[1];   // int64 ref -> int32 in harness
    const float* W1 = (const float*)d_in[2];
    const float* b1 = (const float*)d_in[3];
    const float* W2 = (const float*)d_in[4];
    const float* b2 = (const float*)d_in[5];
    const int* src = ei;
    const int* dst = ei + N_EDGES;
    float* out = (float*)d_out;

    // workspace layout (256B-aligned)
    char* ws = (char*)d_ws;
    size_t off = 0;
    auto alloc = [&](size_t bytes) {
        size_t o = off; off = (off + bytes + 255) & ~(size_t)255; return o;
    };
    float* dinv      = (float*)(ws + alloc(sizeof(float) * N_NODES));
    int*   cnt       = (int*)  (ws + alloc(sizeof(int) * N_NODES));
    int*   row_start = (int*)  (ws + alloc(sizeof(int) * (N_NODES + 1)));
    int*   partS     = (int*)  (ws + alloc(sizeof(int) * (size_t)NS * N_NODES));
    int2*  edge_data = (int2*) (ws + alloc(sizeof(int2) * N_EDGES));
    float* h1        = (float*)(ws + alloc(sizeof(float) * N_NODES * HIDDEN));
    float* rbuf      = (float*)(ws + alloc(sizeof(float) * N_NODES * HIDDEN));
    float* agg2      = (float*)(ws + alloc(sizeof(float) * N_NODES * HIDDEN));
    int*   bsum      = (int*)  (ws + alloc(sizeof(int) * SCAN_BLOCKS));
    int*   boff      = (int*)  (ws + alloc(sizeof(int) * SCAN_BLOCKS));

    const int nodeBlocks  = (N_NODES + 255) / 256;   // 391
    const int aggBlocks   = (N_NODES + 15) / 16;     // 6250
    const int csGrid      = NS * NCH;                // 256 WGs (1 per CU, 8/XCD group)

    k_p1<<<csGrid, 512, 0, stream>>>(dst, partS);
    k_colscan<<<nodeBlocks, 256, 0, stream>>>(partS, cnt, dinv);
    k_scan_a<<<SCAN_BLOCKS, 1024, 0, stream>>>(cnt, bsum);
    k_scan_b<<<1, 128, 0, stream>>>(bsum, boff);
    k_scan_c<<<SCAN_BLOCKS, 1024, 0, stream>>>(cnt, boff, row_start);
    k_p2<<<csGrid, 512, 0, stream>>>(src, dst, partS, row_start, dinv, edge_data);

    k_gemm1<<<nodeBlocks, 256, 0, stream>>>(x, W1, h1);
    k_agg16<true><<<aggBlocks, 256, 0, stream>>>(edge_data, row_start, dinv, h1, b1, rbuf);
    k_agg16<false><<<aggBlocks, 256, 0, stream>>>(edge_data, row_start, dinv, rbuf, nullptr, agg2);
    k_out<<<nodeBlocks, 256, 0, stream>>>(agg2, W2, b2, out);
}

// Round 6
// 581.900 us; speedup vs baseline: 1.1528x; 1.1528x over previous
//
#include <hip/hip_runtime.h>

#define N_NODES 100000
#define N_EDGES 3200000
#define N_FEAT 512
#define HIDDEN 16
#define N_CLASSES 40

#define SCAN_BLOCKS 98   // ceil(100000/1024)

// ---- pass 1 (per-node degree): 32 slices x 7 LDS-chunks of 16384 ----
// grid dim3(NS, NCH): slice s sits at wgids {s, s+32, ...} -> one XCD ->
// slice fetched once per XCD and shared (round-2 measured FETCH ~= ideal).
#define CH    16384
#define NCH   7
#define NS    32
#define SLICE (N_EDGES / NS)       // 100000
#define SL4   (SLICE / 4)          // 25000

// ---- 2-level counting sort for edge placement ----
// 391 chunks of 256 nodes; 256 staging slices of 12500 edges.
// Stage chunk-major: WG c of k_p3 owns a CONTIGUOUS staged segment and a
// ~65 KB slot range -> scattered 8B stores stay in whichever L2 the WG is
// on; every 32B line is written entirely by one WG -> writeback once.
#define CH3   256
#define NCHK  391                  // ceil(100000/256)
#define NS2   256
#define SLICE2 (N_EDGES / NS2)     // 12500
#define SL4_2  (SLICE2 / 4)        // 3125

typedef int v4i __attribute__((ext_vector_type(4)));
typedef int v2i __attribute__((ext_vector_type(2)));

// Pass 1: per-(slice, node) partial histogram via LDS atomics.
__global__ __launch_bounds__(512) void k_p1(const int* __restrict__ dst,
                                            int* __restrict__ partS) {
    __shared__ int hist[CH];
    int tid = threadIdx.x;
    int s = blockIdx.x, j = blockIdx.y;
    int base = j * CH;
    int lim = N_NODES - base; if (lim > CH) lim = CH;
    for (int i = tid; i < CH; i += 512) hist[i] = 0;
    __syncthreads();
    const v4i* dp = reinterpret_cast<const v4i*>(dst + s * SLICE);
    for (int i = tid; i < SL4; i += 512) {
        v4i d4 = __builtin_nontemporal_load(dp + i);
        unsigned a = (unsigned)(d4.x - base); if (a < (unsigned)lim) atomicAdd(&hist[a], 1);
        unsigned b = (unsigned)(d4.y - base); if (b < (unsigned)lim) atomicAdd(&hist[b], 1);
        unsigned c = (unsigned)(d4.z - base); if (c < (unsigned)lim) atomicAdd(&hist[c], 1);
        unsigned d = (unsigned)(d4.w - base); if (d < (unsigned)lim) atomicAdd(&hist[d], 1);
    }
    __syncthreads();
    for (int i = tid; i < lim; i += 512)
        partS[s * N_NODES + base + i] = hist[i];
}

// deg[n] = sum over slices of partS (read-only now), dinv fused.
__global__ __launch_bounds__(256) void k_colscan(const int* __restrict__ partS,
                                                 int* __restrict__ deg,
                                                 float* __restrict__ dinv) {
    int n = blockIdx.x * 256 + threadIdx.x;
    if (n >= N_NODES) return;
    int run = 0;
    #pragma unroll
    for (int s = 0; s < NS; s++) run += partS[s * N_NODES + n];
    deg[n] = run;
    dinv[n] = rsqrtf((float)(run + 1));  // +1 self-loop
}

// ---------------- 3-phase exclusive scan of deg -> row_start ----------------

__global__ __launch_bounds__(1024) void k_scan_a(const int* __restrict__ cnt,
                                                 int* __restrict__ bsum) {
    int tid = threadIdx.x;
    int i = blockIdx.x * 1024 + tid;
    int v = (i < N_NODES) ? cnt[i] : 0;
    #pragma unroll
    for (int off = 32; off >= 1; off >>= 1) v += __shfl_xor(v, off, 64);
    __shared__ int ws[16];
    if ((tid & 63) == 0) ws[tid >> 6] = v;
    __syncthreads();
    if (tid == 0) {
        int s = 0;
        #pragma unroll
        for (int w = 0; w < 16; w++) s += ws[w];
        bsum[blockIdx.x] = s;
    }
}

__global__ __launch_bounds__(128) void k_scan_b(const int* __restrict__ bsum,
                                                int* __restrict__ boff) {
    int tid = threadIdx.x;
    int lane = tid & 63, wv = tid >> 6;
    int v = (tid < SCAN_BLOCKS) ? bsum[tid] : 0;
    int sc = v;
    #pragma unroll
    for (int off = 1; off < 64; off <<= 1) {
        int t = __shfl_up(sc, off, 64);
        if (lane >= off) sc += t;
    }
    __shared__ int wsum[2];
    if (lane == 63) wsum[wv] = sc;
    __syncthreads();
    int pre = (wv == 1) ? wsum[0] : 0;
    if (tid < SCAN_BLOCKS) boff[tid] = pre + sc - v;  // exclusive
}

__global__ __launch_bounds__(1024) void k_scan_c(const int* __restrict__ cnt,
                                                 const int* __restrict__ boff,
                                                 int* __restrict__ row_start) {
    int tid = threadIdx.x;
    int i = blockIdx.x * 1024 + tid;
    int lane = tid & 63, wv = tid >> 6;
    int v = (i < N_NODES) ? cnt[i] : 0;
    int sc = v;
    #pragma unroll
    for (int off = 1; off < 64; off <<= 1) {
        int t = __shfl_up(sc, off, 64);
        if (lane >= off) sc += t;
    }
    __shared__ int wsum[16];
    if (lane == 63) wsum[wv] = sc;
    __syncthreads();
    int pre = 0;
    #pragma unroll
    for (int w = 0; w < 16; w++) pre += (w < wv) ? wsum[w] : 0;
    int excl = boff[blockIdx.x] + pre + sc - v;
    if (i < N_NODES) row_start[i] = excl;
    if (i == N_NODES) row_start[N_NODES] = N_EDGES;
}

// Per-(staging slice, 256-node chunk) counts. 391-bin LDS hist.
__global__ __launch_bounds__(512) void k_p1b(const int* __restrict__ dst,
                                             int* __restrict__ cnt_sc) {
    __shared__ int hist[NCHK];
    int tid = threadIdx.x;
    int s = blockIdx.x;
    for (int i = tid; i < NCHK; i += 512) hist[i] = 0;
    __syncthreads();
    const v4i* dp = reinterpret_cast<const v4i*>(dst + s * SLICE2);
    for (int i = tid; i < SL4_2; i += 512) {
        v4i d4 = __builtin_nontemporal_load(dp + i);
        atomicAdd(&hist[(unsigned)d4.x >> 8], 1);
        atomicAdd(&hist[(unsigned)d4.y >> 8], 1);
        atomicAdd(&hist[(unsigned)d4.z >> 8], 1);
        atomicAdd(&hist[(unsigned)d4.w >> 8], 1);
    }
    __syncthreads();
    for (int i = tid; i < NCHK; i += 512)
        cnt_sc[s * NCHK + i] = hist[i];
}

// Scan cnt_sc: sbase[s][c] = prefix over slices within chunk c (relative);
// cb[c] = chunk-major exclusive base in the staged buffer.
__global__ __launch_bounds__(512) void k_scstage(const int* __restrict__ cnt_sc,
                                                 int* __restrict__ sbase,
                                                 int* __restrict__ cb) {
    int tid = threadIdx.x;
    int tot = 0;
    if (tid < NCHK) {
        int run = 0;
        #pragma unroll 8
        for (int s = 0; s < NS2; s++) {
            int v = cnt_sc[s * NCHK + tid];
            sbase[s * NCHK + tid] = run;
            run += v;
        }
        tot = run;
    }
    // exclusive scan of tot across 512 threads (first NCHK meaningful)
    int lane = tid & 63, wv = tid >> 6;
    int sc = tot;
    #pragma unroll
    for (int off = 1; off < 64; off <<= 1) {
        int t = __shfl_up(sc, off, 64);
        if (lane >= off) sc += t;
    }
    __shared__ int wsum[8];
    if (lane == 63) wsum[wv] = sc;
    __syncthreads();
    int pre = 0;
    #pragma unroll
    for (int w = 0; w < 8; w++) pre += (w < wv) ? wsum[w] : 0;
    int excl = pre + sc - tot;
    if (tid < NCHK) cb[tid] = excl;
    if (tid == NCHK - 1) cb[NCHK] = excl + tot;  // = N_EDGES
}

// Stage edges chunk-major: append {src,dst} at cb[c]+sbase[s][c]+cursor.
// Per-WG write set = 391 active append streams (one 32B sector each) ->
// lines fill completely in L2, writeback ~once.
__global__ __launch_bounds__(512) void k_p2stage(const int* __restrict__ src,
                                                 const int* __restrict__ dst,
                                                 const int* __restrict__ sbase,
                                                 const int* __restrict__ cb,
                                                 int2* __restrict__ staged) {
    __shared__ int curpos[NCHK];
    int tid = threadIdx.x;
    int s = blockIdx.x;
    for (int c = tid; c < NCHK; c += 512)
        curpos[c] = cb[c] + sbase[s * NCHK + c];
    __syncthreads();
    const v4i* dp = reinterpret_cast<const v4i*>(dst + s * SLICE2);
    const v4i* sp = reinterpret_cast<const v4i*>(src + s * SLICE2);
    for (int i = tid; i < SL4_2; i += 512) {
        v4i d4 = __builtin_nontemporal_load(dp + i);
        v4i s4 = __builtin_nontemporal_load(sp + i);
        int p0 = atomicAdd(&curpos[(unsigned)d4.x >> 8], 1);
        staged[p0] = make_int2(s4.x, d4.x);
        int p1 = atomicAdd(&curpos[(unsigned)d4.y >> 8], 1);
        staged[p1] = make_int2(s4.y, d4.y);
        int p2 = atomicAdd(&curpos[(unsigned)d4.z >> 8], 1);
        staged[p2] = make_int2(s4.z, d4.z);
        int p3 = atomicAdd(&curpos[(unsigned)d4.w >> 8], 1);
        staged[p3] = make_int2(s4.w, d4.w);
    }
}

// Final placement: WG c streams its contiguous staged segment, scatters into
// its ~65 KB slot range via LDS cursors. Intra-node edge order is free
// (aggregation is a sum), so cursors start at row_start[n].
__global__ __launch_bounds__(512) void k_p3(const int2* __restrict__ staged,
                                            const int* __restrict__ cb,
                                            const int* __restrict__ row_start,
                                            const float* __restrict__ dinv,
                                            int2* __restrict__ edge_data) {
    __shared__ int cur[CH3];
    __shared__ float dv[CH3];
    int tid = threadIdx.x;
    int c = blockIdx.x;
    int base = c << 8;
    int lim = N_NODES - base; if (lim > CH3) lim = CH3;
    if (tid < lim) {
        cur[tid] = row_start[base + tid];
        dv[tid]  = dinv[base + tid];
    }
    __syncthreads();
    int beg = cb[c], end = cb[c + 1];
    const v2i* stp = reinterpret_cast<const v2i*>(staged);
    for (int i = beg + tid; i < end; i += 512) {
        v2i e = __builtin_nontemporal_load(stp + i);   // {src, dst}
        int nl = e.y - base;
        float nrm = dinv[e.x] * dv[nl];
        int slot = atomicAdd(&cur[nl], 1);
        edge_data[slot] = make_int2(e.x, __float_as_int(nrm));
    }
}

// ---------------- GEMM1: h1[N,16] = x[N,512] @ W1[512,16] ----------------

#define KC 32
#define LDSW 36

__global__ __launch_bounds__(256) void k_gemm1(const float* __restrict__ x,
                                               const float* __restrict__ W1,
                                               float* __restrict__ h1) {
    __shared__ float xs[256 * LDSW];
    int tid = threadIdx.x;
    int row = blockIdx.x * 256 + tid;

    float acc[HIDDEN];
    #pragma unroll
    for (int j = 0; j < HIDDEN; j++) acc[j] = 0.f;

    int s_sub = tid >> 3;  // 0..31 staging row-sub
    int s_k4  = tid & 7;   // 0..7  staging k4

    for (int kc = 0; kc < N_FEAT; kc += KC) {
        __syncthreads();  // previous chunk's reads done before overwrite
        #pragma unroll
        for (int l = 0; l < 8; l++) {
            int srow = s_sub + l * 32;
            int grow = blockIdx.x * 256 + srow;
            int gr = grow < N_NODES ? grow : N_NODES - 1;  // clamp
            float4 v = *reinterpret_cast<const float4*>(
                x + (size_t)gr * N_FEAT + kc + s_k4 * 4);
            *reinterpret_cast<float4*>(&xs[srow * LDSW + s_k4 * 4]) = v;
        }
        __syncthreads();

        const float* Wc = W1 + kc * HIDDEN;  // wave-uniform
        #pragma unroll
        for (int k4 = 0; k4 < 8; k4++) {
            float4 xv = *reinterpret_cast<const float4*>(&xs[tid * LDSW + k4 * 4]);
            const float* w0 = Wc + (k4 * 4 + 0) * HIDDEN;
            const float* w1 = Wc + (k4 * 4 + 1) * HIDDEN;
            const float* w2 = Wc + (k4 * 4 + 2) * HIDDEN;
            const float* w3 = Wc + (k4 * 4 + 3) * HIDDEN;
            #pragma unroll
            for (int j = 0; j < HIDDEN; j++) {
                acc[j] += xv.x * w0[j];
                acc[j] += xv.y * w1[j];
                acc[j] += xv.z * w2[j];
                acc[j] += xv.w * w3[j];
            }
        }
    }

    if (row < N_NODES) {
        float4* op = reinterpret_cast<float4*>(h1 + (size_t)row * HIDDEN);
        #pragma unroll
        for (int q = 0; q < 4; q++)
            op[q] = make_float4(acc[q*4+0], acc[q*4+1], acc[q*4+2], acc[q*4+3]);
    }
}

// ---------------- CSR aggregation over 16 features ----------------

template <bool RELU>
__global__ __launch_bounds__(256) void k_agg16(const int2* __restrict__ edge_data,
                                               const int* __restrict__ row_start,
                                               const float* __restrict__ dinv,
                                               const float* __restrict__ h,
                                               const float* __restrict__ bias,
                                               float* __restrict__ out) {
    int g = threadIdx.x >> 4, j = threadIdx.x & 15;
    int node = blockIdx.x * 16 + g;
    if (node >= N_NODES) return;
    int beg = row_start[node], end = row_start[node + 1];
    float ds = dinv[node];
    float acc = h[(size_t)node * HIDDEN + j] * (ds * ds);  // self loop
    int i = beg;
    for (; i + 3 < end; i += 4) {
        int2 e0 = edge_data[i + 0];
        int2 e1 = edge_data[i + 1];
        int2 e2 = edge_data[i + 2];
        int2 e3 = edge_data[i + 3];
        float v0 = h[(size_t)e0.x * HIDDEN + j];
        float v1 = h[(size_t)e1.x * HIDDEN + j];
        float v2 = h[(size_t)e2.x * HIDDEN + j];
        float v3 = h[(size_t)e3.x * HIDDEN + j];
        acc += v0 * __int_as_float(e0.y);
        acc += v1 * __int_as_float(e1.y);
        acc += v2 * __int_as_float(e2.y);
        acc += v3 * __int_as_float(e3.y);
    }
    for (; i < end; ++i) {
        int2 ed = edge_data[i];
        acc += h[(size_t)ed.x * HIDDEN + j] * __int_as_float(ed.y);
    }
    if (RELU) acc = fmaxf(acc + bias[j], 0.f);
    out[(size_t)node * HIDDEN + j] = acc;
}

// ---------------- final: out = agg2 @ W2 + b2, log_softmax ----------------

__global__ __launch_bounds__(256) void k_out(const float* __restrict__ agg2,
                                             const float* __restrict__ W2,
                                             const float* __restrict__ b2,
                                             float* __restrict__ out) {
    int r = blockIdx.x * 256 + threadIdx.x;
    if (r >= N_NODES) return;
    float a[HIDDEN];
    const float4* ap = reinterpret_cast<const float4*>(agg2 + (size_t)r * HIDDEN);
    #pragma unroll
    for (int q = 0; q < 4; q++) {
        float4 v = ap[q];
        a[q * 4 + 0] = v.x; a[q * 4 + 1] = v.y;
        a[q * 4 + 2] = v.z; a[q * 4 + 3] = v.w;
    }
    float acc[N_CLASSES];
    #pragma unroll
    for (int jj = 0; jj < N_CLASSES; jj++) acc[jj] = b2[jj];
    #pragma unroll
    for (int kk = 0; kk < HIDDEN; kk++) {
        float av = a[kk];
        #pragma unroll
        for (int jj = 0; jj < N_CLASSES; jj++)
            acc[jj] += av * W2[kk * N_CLASSES + jj];  // uniform -> scalar loads
    }
    float m = -1e30f;
    #pragma unroll
    for (int jj = 0; jj < N_CLASSES; jj++) m = fmaxf(m, acc[jj]);
    float sum = 0.f;
    #pragma unroll
    for (int jj = 0; jj < N_CLASSES; jj++) sum += __expf(acc[jj] - m);
    float l = m + __logf(sum);
    float4* op = reinterpret_cast<float4*>(out + (size_t)r * N_CLASSES);
    #pragma unroll
    for (int q = 0; q < N_CLASSES / 4; q++) {
        op[q] = make_float4(acc[q*4+0] - l, acc[q*4+1] - l,
                            acc[q*4+2] - l, acc[q*4+3] - l);
    }
}

// ---------------- launch ----------------

extern "C" void kernel_launch(void* const* d_in, const int* in_sizes, int n_in,
                              void* d_out, int out_size, void* d_ws, size_t ws_size,
                              hipStream_t stream) {
    const float* x  = (const float*)d_in[0];
    const int*   ei = (const int*)d_in[1];   // int64 ref -> int32 in harness
    const float* W1 = (const float*)d_in[2];
    const float* b1 = (const float*)d_in[3];
    const float* W2 = (const float*)d_in[4];
    const float* b2 = (const float*)d_in[5];
    const int* src = ei;
    const int* dst = ei + N_EDGES;
    float* out = (float*)d_out;

    // workspace layout (256B-aligned, ~60 MB total)
    char* ws = (char*)d_ws;
    size_t off = 0;
    auto alloc = [&](size_t bytes) {
        size_t o = off; off = (off + bytes + 255) & ~(size_t)255; return o;
    };
    float* dinv      = (float*)(ws + alloc(sizeof(float) * N_NODES));
    int*   cnt       = (int*)  (ws + alloc(sizeof(int) * N_NODES));
    int*   row_start = (int*)  (ws + alloc(sizeof(int) * (N_NODES + 1)));
    int*   cnt_sc    = (int*)  (ws + alloc(sizeof(int) * NS2 * NCHK));
    int*   sbase     = (int*)  (ws + alloc(sizeof(int) * NS2 * NCHK));
    int*   cb        = (int*)  (ws + alloc(sizeof(int) * (NCHK + 1)));
    // partS, h1, rbuf are consecutive and 256B-size-aligned: together they
    // form exactly 25.6 MB = the staged {src,dst} buffer (alias). partS is
    // dead after k_colscan; h1/rbuf are first written after k_p3 consumed
    // staged. All launches are in-order on one stream.
    int*   partS     = (int*)  (ws + alloc(sizeof(int) * (size_t)NS * N_NODES));
    float* h1        = (float*)(ws + alloc(sizeof(float) * N_NODES * HIDDEN));
    float* rbuf      = (float*)(ws + alloc(sizeof(float) * N_NODES * HIDDEN));
    int2*  staged    = (int2*)partS;   // 3.2M int2 == 25.6 MB
    int2*  edge_data = (int2*) (ws + alloc(sizeof(int2) * N_EDGES));
    float* agg2      = (float*)(ws + alloc(sizeof(float) * N_NODES * HIDDEN));
    int*   bsum      = (int*)  (ws + alloc(sizeof(int) * SCAN_BLOCKS));
    int*   boff      = (int*)  (ws + alloc(sizeof(int) * SCAN_BLOCKS));

    const int nodeBlocks  = (N_NODES + 255) / 256;   // 391
    const int aggBlocks   = (N_NODES + 15) / 16;     // 6250

    k_p1<<<dim3(NS, NCH), 512, 0, stream>>>(dst, partS);
    k_p1b<<<NS2, 512, 0, stream>>>(dst, cnt_sc);
    k_colscan<<<nodeBlocks, 256, 0, stream>>>(partS, cnt, dinv);
    k_scan_a<<<SCAN_BLOCKS, 1024, 0, stream>>>(cnt, bsum);
    k_scan_b<<<1, 128, 0, stream>>>(bsum, boff);
    k_scan_c<<<SCAN_BLOCKS, 1024, 0, stream>>>(cnt, boff, row_start);
    k_scstage<<<1, 512, 0, stream>>>(cnt_sc, sbase, cb);
    k_p2stage<<<NS2, 512, 0, stream>>>(src, dst, sbase, cb, staged);
    k_p3<<<NCHK, 512, 0, stream>>>(staged, cb, row_start, dinv, edge_data);

    k_gemm1<<<nodeBlocks, 256, 0, stream>>>(x, W1, h1);
    k_agg16<true><<<aggBlocks, 256, 0, stream>>>(edge_data, row_start, dinv, h1, b1, rbuf);
    k_agg16<false><<<aggBlocks, 256, 0, stream>>>(edge_data, row_start, dinv, rbuf, nullptr, agg2);
    k_out<<<nodeBlocks, 256, 0, stream>>>(agg2, W2, b2, out);
}

// Round 7
// 570.967 us; speedup vs baseline: 1.1749x; 1.0191x over previous
//
#include <hip/hip_runtime.h>

#define N_NODES 100000
#define N_EDGES 3200000
#define N_FEAT 512
#define HIDDEN 16
#define N_CLASSES 40

#define SCAN_BLOCKS 98   // ceil(100000/1024)

// ---- 2-level counting sort for edge placement ----
// 391 chunks of 256 nodes; 256 staging slices of 12500 edges.
// Stage chunk-major: WG c of k_p3 owns a CONTIGUOUS staged segment and a
// ~65 KB slot range -> scattered 8B stores stay in whichever L2 the WG is
// on; every 32B line is written entirely by one WG -> writeback once.
// Per-node degree is derived FROM the staged buffer (k_deg) -- the old
// 7x-re-read 64KB-LDS histogram kernel (k_p1) and k_colscan are gone.
#define CH3   256
#define NCHK  391                  // ceil(100000/256)
#define NS2   256
#define SLICE2 (N_EDGES / NS2)     // 12500
#define SL4_2  (SLICE2 / 4)        // 3125

typedef int v4i __attribute__((ext_vector_type(4)));
typedef int v2i __attribute__((ext_vector_type(2)));

// Per-(staging slice, 256-node chunk) counts. 391-bin LDS hist.
__global__ __launch_bounds__(512) void k_p1b(const int* __restrict__ dst,
                                             int* __restrict__ cnt_sc) {
    __shared__ int hist[NCHK];
    int tid = threadIdx.x;
    int s = blockIdx.x;
    for (int i = tid; i < NCHK; i += 512) hist[i] = 0;
    __syncthreads();
    const v4i* dp = reinterpret_cast<const v4i*>(dst + s * SLICE2);
    for (int i = tid; i < SL4_2; i += 512) {
        v4i d4 = __builtin_nontemporal_load(dp + i);
        atomicAdd(&hist[(unsigned)d4.x >> 8], 1);
        atomicAdd(&hist[(unsigned)d4.y >> 8], 1);
        atomicAdd(&hist[(unsigned)d4.z >> 8], 1);
        atomicAdd(&hist[(unsigned)d4.w >> 8], 1);
    }
    __syncthreads();
    for (int i = tid; i < NCHK; i += 512)
        cnt_sc[s * NCHK + i] = hist[i];
}

// Parallel slice-scan: one WAVE per chunk (391 waves across 98 WGs).
// sbase[s][c] = exclusive prefix over slices s within chunk c; tot[c] = sum.
// Replaces the old 1-WG serial k_scstage (a single-CU straggler).
__global__ __launch_bounds__(256) void k_scstage2(const int* __restrict__ cnt_sc,
                                                  int* __restrict__ sbase,
                                                  int* __restrict__ tot) {
    int c = blockIdx.x * 4 + (threadIdx.x >> 6);
    int lane = threadIdx.x & 63;
    if (c >= NCHK) return;
    int carry = 0;
    #pragma unroll
    for (int r = 0; r < 4; r++) {
        int s = r * 64 + lane;
        int v = cnt_sc[s * NCHK + c];
        int sc = v;
        #pragma unroll
        for (int off = 1; off < 64; off <<= 1) {
            int t = __shfl_up(sc, off, 64);
            if (lane >= off) sc += t;
        }
        sbase[s * NCHK + c] = carry + sc - v;   // exclusive within chunk
        carry += __shfl(sc, 63, 64);            // round total
    }
    if (lane == 0) tot[c] = carry;
}

// Tiny scan of tot[391] -> cb[0..391] (chunk bases in the staged buffer).
__global__ __launch_bounds__(512) void k_cbscan(const int* __restrict__ tot,
                                                int* __restrict__ cb) {
    int tid = threadIdx.x;
    int v = (tid < NCHK) ? tot[tid] : 0;
    int lane = tid & 63, wv = tid >> 6;
    int sc = v;
    #pragma unroll
    for (int off = 1; off < 64; off <<= 1) {
        int t = __shfl_up(sc, off, 64);
        if (lane >= off) sc += t;
    }
    __shared__ int wsum[8];
    if (lane == 63) wsum[wv] = sc;
    __syncthreads();
    int pre = 0;
    #pragma unroll
    for (int w = 0; w < 8; w++) pre += (w < wv) ? wsum[w] : 0;
    int excl = pre + sc - v;
    if (tid < NCHK) cb[tid] = excl;
    if (tid == NCHK - 1) cb[NCHK] = excl + v;   // = N_EDGES
}

// Stage edges chunk-major: append {src,dst} at cb[c]+sbase[s][c]+cursor.
// Per-WG write set = 391 active append streams (one 32B sector each) ->
// lines fill completely in L2, writeback ~once.
__global__ __launch_bounds__(512) void k_p2stage(const int* __restrict__ src,
                                                 const int* __restrict__ dst,
                                                 const int* __restrict__ sbase,
                                                 const int* __restrict__ cb,
                                                 int2* __restrict__ staged) {
    __shared__ int curpos[NCHK];
    int tid = threadIdx.x;
    int s = blockIdx.x;
    for (int c = tid; c < NCHK; c += 512)
        curpos[c] = cb[c] + sbase[s * NCHK + c];
    __syncthreads();
    const v4i* dp = reinterpret_cast<const v4i*>(dst + s * SLICE2);
    const v4i* sp = reinterpret_cast<const v4i*>(src + s * SLICE2);
    for (int i = tid; i < SL4_2; i += 512) {
        v4i d4 = __builtin_nontemporal_load(dp + i);
        v4i s4 = __builtin_nontemporal_load(sp + i);
        int p0 = atomicAdd(&curpos[(unsigned)d4.x >> 8], 1);
        staged[p0] = make_int2(s4.x, d4.x);
        int p1 = atomicAdd(&curpos[(unsigned)d4.y >> 8], 1);
        staged[p1] = make_int2(s4.y, d4.y);
        int p2 = atomicAdd(&curpos[(unsigned)d4.z >> 8], 1);
        staged[p2] = make_int2(s4.z, d4.z);
        int p3 = atomicAdd(&curpos[(unsigned)d4.w >> 8], 1);
        staged[p3] = make_int2(s4.w, d4.w);
    }
}

// Degree + dinv from the staged buffer: WG c streams its contiguous segment
// (L2/L3-hot, just written) and LDS-counts its 256 nodes. PLAIN loads here
// (k_p3 re-reads staged; nt would evict it early).
__global__ __launch_bounds__(256) void k_deg(const int2* __restrict__ staged,
                                             const int* __restrict__ cb,
                                             int* __restrict__ deg,
                                             float* __restrict__ dinv) {
    __shared__ int cnt[CH3];
    int tid = threadIdx.x;
    int c = blockIdx.x;
    int base = c << 8;
    int lim = N_NODES - base; if (lim > CH3) lim = CH3;
    cnt[tid] = 0;
    __syncthreads();
    int beg = cb[c], end = cb[c + 1];
    const v2i* stp = reinterpret_cast<const v2i*>(staged);
    for (int i = beg + tid; i < end; i += 256) {
        v2i e = stp[i];
        atomicAdd(&cnt[e.y - base], 1);
    }
    __syncthreads();
    if (tid < lim) {
        int d = cnt[tid];
        deg[base + tid] = d;
        dinv[base + tid] = rsqrtf((float)(d + 1));  // +1 self-loop
    }
}

// ---------------- 3-phase exclusive scan of deg -> row_start ----------------

__global__ __launch_bounds__(1024) void k_scan_a(const int* __restrict__ cnt,
                                                 int* __restrict__ bsum) {
    int tid = threadIdx.x;
    int i = blockIdx.x * 1024 + tid;
    int v = (i < N_NODES) ? cnt[i] : 0;
    #pragma unroll
    for (int off = 32; off >= 1; off >>= 1) v += __shfl_xor(v, off, 64);
    __shared__ int ws[16];
    if ((tid & 63) == 0) ws[tid >> 6] = v;
    __syncthreads();
    if (tid == 0) {
        int s = 0;
        #pragma unroll
        for (int w = 0; w < 16; w++) s += ws[w];
        bsum[blockIdx.x] = s;
    }
}

__global__ __launch_bounds__(128) void k_scan_b(const int* __restrict__ bsum,
                                                int* __restrict__ boff) {
    int tid = threadIdx.x;
    int lane = tid & 63, wv = tid >> 6;
    int v = (tid < SCAN_BLOCKS) ? bsum[tid] : 0;
    int sc = v;
    #pragma unroll
    for (int off = 1; off < 64; off <<= 1) {
        int t = __shfl_up(sc, off, 64);
        if (lane >= off) sc += t;
    }
    __shared__ int wsum[2];
    if (lane == 63) wsum[wv] = sc;
    __syncthreads();
    int pre = (wv == 1) ? wsum[0] : 0;
    if (tid < SCAN_BLOCKS) boff[tid] = pre + sc - v;  // exclusive
}

__global__ __launch_bounds__(1024) void k_scan_c(const int* __restrict__ cnt,
                                                 const int* __restrict__ boff,
                                                 int* __restrict__ row_start) {
    int tid = threadIdx.x;
    int i = blockIdx.x * 1024 + tid;
    int lane = tid & 63, wv = tid >> 6;
    int v = (i < N_NODES) ? cnt[i] : 0;
    int sc = v;
    #pragma unroll
    for (int off = 1; off < 64; off <<= 1) {
        int t = __shfl_up(sc, off, 64);
        if (lane >= off) sc += t;
    }
    __shared__ int wsum[16];
    if (lane == 63) wsum[wv] = sc;
    __syncthreads();
    int pre = 0;
    #pragma unroll
    for (int w = 0; w < 16; w++) pre += (w < wv) ? wsum[w] : 0;
    int excl = boff[blockIdx.x] + pre + sc - v;
    if (i < N_NODES) row_start[i] = excl;
    if (i == N_NODES) row_start[N_NODES] = N_EDGES;
}

// Final placement: WG c streams its contiguous staged segment, scatters into
// its ~65 KB slot range via LDS cursors. Intra-node edge order is free
// (aggregation is a sum), so cursors start at row_start[n].
__global__ __launch_bounds__(512) void k_p3(const int2* __restrict__ staged,
                                            const int* __restrict__ cb,
                                            const int* __restrict__ row_start,
                                            const float* __restrict__ dinv,
                                            int2* __restrict__ edge_data) {
    __shared__ int cur[CH3];
    __shared__ float dv[CH3];
    int tid = threadIdx.x;
    int c = blockIdx.x;
    int base = c << 8;
    int lim = N_NODES - base; if (lim > CH3) lim = CH3;
    if (tid < lim) {
        cur[tid] = row_start[base + tid];
        dv[tid]  = dinv[base + tid];
    }
    __syncthreads();
    int beg = cb[c], end = cb[c + 1];
    const v2i* stp = reinterpret_cast<const v2i*>(staged);
    for (int i = beg + tid; i < end; i += 512) {
        v2i e = __builtin_nontemporal_load(stp + i);   // {src, dst}; last read
        int nl = e.y - base;
        float nrm = dinv[e.x] * dv[nl];
        int slot = atomicAdd(&cur[nl], 1);
        edge_data[slot] = make_int2(e.x, __float_as_int(nrm));
    }
}

// ---------------- GEMM1: h1[N,16] = x[N,512] @ W1[512,16] ----------------

#define KC 32
#define LDSW 36

__global__ __launch_bounds__(256) void k_gemm1(const float* __restrict__ x,
                                               const float* __restrict__ W1,
                                               float* __restrict__ h1) {
    __shared__ float xs[256 * LDSW];
    int tid = threadIdx.x;
    int row = blockIdx.x * 256 + tid;

    float acc[HIDDEN];
    #pragma unroll
    for (int j = 0; j < HIDDEN; j++) acc[j] = 0.f;

    int s_sub = tid >> 3;  // 0..31 staging row-sub
    int s_k4  = tid & 7;   // 0..7  staging k4

    for (int kc = 0; kc < N_FEAT; kc += KC) {
        __syncthreads();  // previous chunk's reads done before overwrite
        #pragma unroll
        for (int l = 0; l < 8; l++) {
            int srow = s_sub + l * 32;
            int grow = blockIdx.x * 256 + srow;
            int gr = grow < N_NODES ? grow : N_NODES - 1;  // clamp
            float4 v = *reinterpret_cast<const float4*>(
                x + (size_t)gr * N_FEAT + kc + s_k4 * 4);
            *reinterpret_cast<float4*>(&xs[srow * LDSW + s_k4 * 4]) = v;
        }
        __syncthreads();

        const float* Wc = W1 + kc * HIDDEN;  // wave-uniform
        #pragma unroll
        for (int k4 = 0; k4 < 8; k4++) {
            float4 xv = *reinterpret_cast<const float4*>(&xs[tid * LDSW + k4 * 4]);
            const float* w0 = Wc + (k4 * 4 + 0) * HIDDEN;
            const float* w1 = Wc + (k4 * 4 + 1) * HIDDEN;
            const float* w2 = Wc + (k4 * 4 + 2) * HIDDEN;
            const float* w3 = Wc + (k4 * 4 + 3) * HIDDEN;
            #pragma unroll
            for (int j = 0; j < HIDDEN; j++) {
                acc[j] += xv.x * w0[j];
                acc[j] += xv.y * w1[j];
                acc[j] += xv.z * w2[j];
                acc[j] += xv.w * w3[j];
            }
        }
    }

    if (row < N_NODES) {
        float4* op = reinterpret_cast<float4*>(h1 + (size_t)row * HIDDEN);
        #pragma unroll
        for (int q = 0; q < 4; q++)
            op[q] = make_float4(acc[q*4+0], acc[q*4+1], acc[q*4+2], acc[q*4+3]);
    }
}

// ---------------- CSR aggregation: one WAVE per node ----------------
// lane = sub*16 + j: sub = 4 parallel edge chains, j = feature. Uniform
// trip count per wave (no cross-node divergence); 16-wide unroll keeps
// 16 outstanding loads/wave; shuffle-reduce folds the 4 subs.

template <bool RELU>
__global__ __launch_bounds__(256) void k_aggw(const int2* __restrict__ edge_data,
                                              const int* __restrict__ row_start,
                                              const float* __restrict__ dinv,
                                              const float* __restrict__ h,
                                              const float* __restrict__ bias,
                                              float* __restrict__ out) {
    int lane = threadIdx.x & 63;
    int node = blockIdx.x * 4 + (threadIdx.x >> 6);
    int sub = lane >> 4, j = lane & 15;
    int beg = row_start[node], end = row_start[node + 1];
    float ds = dinv[node];
    float acc = (sub == 0) ? h[(size_t)node * HIDDEN + j] * (ds * ds) : 0.f;
    int i = beg + sub;
    for (; i + 12 < end; i += 16) {
        int2 ea = edge_data[i];
        int2 eb = edge_data[i + 4];
        int2 ec = edge_data[i + 8];
        int2 ed = edge_data[i + 12];
        float va = h[(size_t)ea.x * HIDDEN + j];
        float vb = h[(size_t)eb.x * HIDDEN + j];
        float vc = h[(size_t)ec.x * HIDDEN + j];
        float vd = h[(size_t)ed.x * HIDDEN + j];
        acc += va * __int_as_float(ea.y);
        acc += vb * __int_as_float(eb.y);
        acc += vc * __int_as_float(ec.y);
        acc += vd * __int_as_float(ed.y);
    }
    for (; i < end; i += 4) {
        int2 e = edge_data[i];
        acc += h[(size_t)e.x * HIDDEN + j] * __int_as_float(e.y);
    }
    acc += __shfl_xor(acc, 16, 64);
    acc += __shfl_xor(acc, 32, 64);
    if (sub == 0) {
        if (RELU) acc = fmaxf(acc + bias[j], 0.f);
        out[(size_t)node * HIDDEN + j] = acc;
    }
}

// ---------------- final: out = agg2 @ W2 + b2, log_softmax ----------------

__global__ __launch_bounds__(256) void k_out(const float* __restrict__ agg2,
                                             const float* __restrict__ W2,
                                             const float* __restrict__ b2,
                                             float* __restrict__ out) {
    int r = blockIdx.x * 256 + threadIdx.x;
    if (r >= N_NODES) return;
    float a[HIDDEN];
    const float4* ap = reinterpret_cast<const float4*>(agg2 + (size_t)r * HIDDEN);
    #pragma unroll
    for (int q = 0; q < 4; q++) {
        float4 v = ap[q];
        a[q * 4 + 0] = v.x; a[q * 4 + 1] = v.y;
        a[q * 4 + 2] = v.z; a[q * 4 + 3] = v.w;
    }
    float acc[N_CLASSES];
    #pragma unroll
    for (int jj = 0; jj < N_CLASSES; jj++) acc[jj] = b2[jj];
    #pragma unroll
    for (int kk = 0; kk < HIDDEN; kk++) {
        float av = a[kk];
        #pragma unroll
        for (int jj = 0; jj < N_CLASSES; jj++)
            acc[jj] += av * W2[kk * N_CLASSES + jj];  // uniform -> scalar loads
    }
    float m = -1e30f;
    #pragma unroll
    for (int jj = 0; jj < N_CLASSES; jj++) m = fmaxf(m, acc[jj]);
    float sum = 0.f;
    #pragma unroll
    for (int jj = 0; jj < N_CLASSES; jj++) sum += __expf(acc[jj] - m);
    float l = m + __logf(sum);
    float4* op = reinterpret_cast<float4*>(out + (size_t)r * N_CLASSES);
    #pragma unroll
    for (int q = 0; q < N_CLASSES / 4; q++) {
        op[q] = make_float4(acc[q*4+0] - l, acc[q*4+1] - l,
                            acc[q*4+2] - l, acc[q*4+3] - l);
    }
}

// ---------------- launch ----------------

extern "C" void kernel_launch(void* const* d_in, const int* in_sizes, int n_in,
                              void* d_out, int out_size, void* d_ws, size_t ws_size,
                              hipStream_t stream) {
    const float* x  = (const float*)d_in[0];
    const int*   ei = (const int*)d_in[1];   // int64 ref -> int32 in harness
    const float* W1 = (const float*)d_in[2];
    const float* b1 = (const float*)d_in[3];
    const float* W2 = (const float*)d_in[4];
    const float* b2 = (const float*)d_in[5];
    const int* src = ei;
    const int* dst = ei + N_EDGES;
    float* out = (float*)d_out;

    // workspace layout (256B-aligned, ~60 MB total)
    char* ws = (char*)d_ws;
    size_t off = 0;
    auto alloc = [&](size_t bytes) {
        size_t o = off; off = (off + bytes + 255) & ~(size_t)255; return o;
    };
    float* dinv      = (float*)(ws + alloc(sizeof(float) * N_NODES));
    int*   cnt       = (int*)  (ws + alloc(sizeof(int) * N_NODES));
    int*   row_start = (int*)  (ws + alloc(sizeof(int) * (N_NODES + 1)));
    int*   cnt_sc    = (int*)  (ws + alloc(sizeof(int) * NS2 * NCHK));
    int*   sbase     = (int*)  (ws + alloc(sizeof(int) * NS2 * NCHK));
    int*   cb        = (int*)  (ws + alloc(sizeof(int) * (NCHK + 1)));
    int*   tot       = (int*)  (ws + alloc(sizeof(int) * NCHK));
    // staged region (25.6 MB) aliases h1+rbuf+pad: staged is consumed by
    // k_deg/k_p3 before gemm1 writes h1. All launches in-order on stream.
    int2*  staged    = (int2*) (ws + alloc(sizeof(int2) * N_EDGES));
    float* h1        = (float*)(ws + off - (size_t)N_EDGES * sizeof(int2));
    float* rbuf      = h1 + (size_t)N_NODES * HIDDEN;
    int2*  edge_data = (int2*) (ws + alloc(sizeof(int2) * N_EDGES));
    float* agg2      = (float*)(ws + alloc(sizeof(float) * N_NODES * HIDDEN));
    int*   bsum      = (int*)  (ws + alloc(sizeof(int) * SCAN_BLOCKS));
    int*   boff      = (int*)  (ws + alloc(sizeof(int) * SCAN_BLOCKS));

    const int nodeBlocks = (N_NODES + 255) / 256;   // 391
    const int aggBlocks  = N_NODES / 4;             // 25000

    k_p1b<<<NS2, 512, 0, stream>>>(dst, cnt_sc);
    k_scstage2<<<(NCHK + 3) / 4, 256, 0, stream>>>(cnt_sc, sbase, tot);
    k_cbscan<<<1, 512, 0, stream>>>(tot, cb);
    k_p2stage<<<NS2, 512, 0, stream>>>(src, dst, sbase, cb, staged);
    k_deg<<<NCHK, 256, 0, stream>>>(staged, cb, cnt, dinv);
    k_scan_a<<<SCAN_BLOCKS, 1024, 0, stream>>>(cnt, bsum);
    k_scan_b<<<1, 128, 0, stream>>>(bsum, boff);
    k_scan_c<<<SCAN_BLOCKS, 1024, 0, stream>>>(cnt, boff, row_start);
    k_p3<<<NCHK, 512, 0, stream>>>(staged, cb, row_start, dinv, edge_data);

    k_gemm1<<<nodeBlocks, 256, 0, stream>>>(x, W1, h1);
    k_aggw<true><<<aggBlocks, 256, 0, stream>>>(edge_data, row_start, dinv, h1, b1, rbuf);
    k_aggw<false><<<aggBlocks, 256, 0, stream>>>(edge_data, row_start, dinv, rbuf, nullptr, agg2);
    k_out<<<nodeBlocks, 256, 0, stream>>>(agg2, W2, b2, out);
}